// Round 3
// baseline (493.403 us; speedup 1.0000x reference)
//
#include <hip/hip_runtime.h>

#define SCAN_THREADS 256
#define EPT 8
#define CHUNK (SCAN_THREADS * EPT)   // 2048 elements per scan chunk
#define COOP_BLOCKS 1024             // __launch_bounds__(256,4) -> 4 blocks/CU * 256 CUs

typedef int   v4i __attribute__((ext_vector_type(4)));
typedef float v4f __attribute__((ext_vector_type(4)));

// ---------------------------------------------------------------------------
// Hand-rolled grid barrier: generation-based, agent-scope atomics, tiny sleep.
// cg::grid_group::sync() on ROCm uses escalating s_sleep backoff (~100us/sync
// at 1024 blocks — measured round 1: 354us kernel, VALUBusy 0.5%). This one
// costs ~serialized-atomic-arrival (~3-4us) + L2 writeback of dirty phase data.
// gen is never reset (compare-based, tolerates any initial value); cnt is
// zeroed by k1 each iteration before this kernel launches (stream-ordered).
// __threadfence() = agent-scope fence (this ROCm lacks __hip_atomic_thread_fence).
__device__ __forceinline__ void grid_barrier(int* cnt, int* gen, int nblocks) {
    __syncthreads();
    if (threadIdx.x == 0) {
        int g = __hip_atomic_load(gen, __ATOMIC_RELAXED, __HIP_MEMORY_SCOPE_AGENT);
        // release: publish this block's phase writes before arrival is visible
        __threadfence();
        int prev = __hip_atomic_fetch_add(cnt, 1, __ATOMIC_ACQ_REL,
                                          __HIP_MEMORY_SCOPE_AGENT);
        if (prev == nblocks - 1) {
            __hip_atomic_store(cnt, 0, __ATOMIC_RELAXED, __HIP_MEMORY_SCOPE_AGENT);
            __hip_atomic_fetch_add(gen, 1, __ATOMIC_RELEASE,
                                   __HIP_MEMORY_SCOPE_AGENT);
        } else {
            while (__hip_atomic_load(gen, __ATOMIC_RELAXED,
                                     __HIP_MEMORY_SCOPE_AGENT) == g) {
                __builtin_amdgcn_s_sleep(1);   // ~64cy poll interval, no backoff
            }
        }
        // acquire: order subsequent phase reads after observing the new gen
        __threadfence();
    }
    __syncthreads();
}

// ---------------------------------------------------------------------------
// K1: filtered = residues * sigmoid(attrs @ w + b); scatter +/- into delta.
// tpre u tpost is a permutation of [0,2N) -> every slot written exactly once.
// Also zeroes the grid-barrier arrival counter for the fused kernel.
__global__ void k1_filter_scatter(const float* __restrict__ attrs,
                                  const float* __restrict__ weight,
                                  const float* __restrict__ bias,
                                  const float* __restrict__ residues,
                                  const int* __restrict__ tpre,
                                  const int* __restrict__ tpost,
                                  float* __restrict__ delta,
                                  int* bar_cnt,
                                  int N) {
    if (bar_cnt && blockIdx.x == 0 && threadIdx.x == 0) *bar_cnt = 0;
    int u0 = (blockIdx.x * blockDim.x + threadIdx.x) * 2;
    v4f w0 = *(const v4f*)weight;
    v4f w1 = *(const v4f*)(weight + 4);
    float b = bias[0];
    if (u0 + 2 <= N) {
        float r0 = residues[u0], r1 = residues[u0 + 1];
        int pre0 = tpre[u0],  pre1 = tpre[u0 + 1];
        int pos0 = tpost[u0], pos1 = tpost[u0 + 1];
        v4f a00 = *(const v4f*)(attrs + (size_t)u0 * 8);
        v4f a01 = *(const v4f*)(attrs + (size_t)u0 * 8 + 4);
        v4f a10 = *(const v4f*)(attrs + (size_t)u0 * 8 + 8);
        v4f a11 = *(const v4f*)(attrs + (size_t)u0 * 8 + 12);
        float l0 = a00.x*w0.x + a00.y*w0.y + a00.z*w0.z + a00.w*w0.w +
                   a01.x*w1.x + a01.y*w1.y + a01.z*w1.z + a01.w*w1.w + b;
        float l1 = a10.x*w0.x + a10.y*w0.y + a10.z*w0.z + a10.w*w0.w +
                   a11.x*w1.x + a11.y*w1.y + a11.z*w1.z + a11.w*w1.w + b;
        float f0 = r0 / (1.0f + __expf(-l0));
        float f1 = r1 / (1.0f + __expf(-l1));
        delta[pre0] =  f0; delta[pre1] =  f1;
        delta[pos0] = -f0; delta[pos1] = -f1;
    } else {
        for (int u = u0; u < N; ++u) {
            float logit = b;
            #pragma unroll
            for (int k = 0; k < 8; ++k) logit += attrs[(size_t)u * 8 + k] * weight[k];
            float f = residues[u] / (1.0f + __expf(-logit));
            delta[tpre[u]]  =  f;
            delta[tpost[u]] = -f;
        }
    }
}

// ---------------------------------------------------------------------------
// Fused cooperative kernel: (P1) chunk partial sums, (P2) in-place chunk scan
// with self-derived offsets, (P3) vnode[u] = ycum[tpre[u]], (P4) pixel gather.
// Hand-rolled barriers replace cg::grid.sync (the round-1 regression source).
__global__ __launch_bounds__(SCAN_THREADS, 4)
void k_fused(float* __restrict__ delta,       // [T] scatter result -> becomes ycum
             float* __restrict__ partials,    // [numChunks]
             float* __restrict__ vnode,       // [N]
             const int* __restrict__ tpre,
             const int* __restrict__ nop,
             float* __restrict__ out,
             int* bar_cnt, int* bar_gen,
             int N, int T, int P, int numChunks)
{
    __shared__ float smem[8];
    const int tid  = threadIdx.x;
    const int lane = tid & 63, wid = tid >> 6;

    // ---- Phase 1: per-chunk partial sums ----
    for (int cch = blockIdx.x; cch < numChunks; cch += gridDim.x) {
        int base = cch * CHUNK + tid * EPT;
        float s = 0.0f;
        if (base + EPT <= T) {
            v4f v0 = *(const v4f*)(delta + base);
            v4f v1 = *(const v4f*)(delta + base + 4);
            s = v0.x + v0.y + v0.z + v0.w + v1.x + v1.y + v1.z + v1.w;
        } else {
            for (int i = 0; i < EPT; ++i)
                if (base + i < T) s += delta[base + i];
        }
        #pragma unroll
        for (int d = 32; d > 0; d >>= 1) s += __shfl_down(s, d, 64);
        if (lane == 0) smem[wid] = s;
        __syncthreads();
        if (tid == 0) partials[cch] = smem[0] + smem[1] + smem[2] + smem[3];
        __syncthreads();
    }
    grid_barrier(bar_cnt, bar_gen, gridDim.x);

    // ---- Phase 2: scan each chunk in place; offset = sum partials[0..c) ----
    for (int cch = blockIdx.x; cch < numChunks; cch += gridDim.x) {
        float c = 0.0f;
        for (int i = tid; i < cch; i += SCAN_THREADS) c += partials[i];
        #pragma unroll
        for (int d = 32; d > 0; d >>= 1) c += __shfl_down(c, d, 64);
        if (lane == 0) smem[4 + wid] = c;

        int base = cch * CHUNK + tid * EPT;
        float v[EPT];
        bool full = (base + EPT <= T);
        if (full) {
            v4f v0 = *(const v4f*)(delta + base);
            v4f v1 = *(const v4f*)(delta + base + 4);
            v[0]=v0.x; v[1]=v0.y; v[2]=v0.z; v[3]=v0.w;
            v[4]=v1.x; v[5]=v1.y; v[6]=v1.z; v[7]=v1.w;
        } else {
            for (int i = 0; i < EPT; ++i)
                v[i] = (base + i < T) ? delta[base + i] : 0.0f;
        }
        float run = 0.0f;
        #pragma unroll
        for (int i = 0; i < EPT; ++i) { run += v[i]; v[i] = run; }
        float tot = run;
        float x = tot;
        #pragma unroll
        for (int d = 1; d < 64; d <<= 1) {
            float y = __shfl_up(x, d, 64);
            if (lane >= d) x += y;
        }
        if (lane == 63) smem[wid] = x;
        __syncthreads();
        float woff = 0.0f, offset = smem[4] + smem[5] + smem[6] + smem[7];
        #pragma unroll
        for (int i = 0; i < SCAN_THREADS / 64; ++i)
            if (i < wid) woff += smem[i];
        float add = (x - tot) + woff + offset;
        if (full) {
            v4f o0 = { v[0]+add, v[1]+add, v[2]+add, v[3]+add };
            v4f o1 = { v[4]+add, v[5]+add, v[6]+add, v[7]+add };
            *(v4f*)(delta + base)     = o0;
            *(v4f*)(delta + base + 4) = o1;
        } else {
            for (int i = 0; i < EPT; ++i)
                if (base + i < T) delta[base + i] = v[i] + add;
        }
        __syncthreads();
    }
    grid_barrier(bar_cnt, bar_gen, gridDim.x);

    // ---- Phase 3: vnode[u] = ycum[tpre[u]] ----
    {
        int u0 = (blockIdx.x * SCAN_THREADS + tid) * 2;
        if (u0 + 2 <= N) {
            int t0 = tpre[u0], t1 = tpre[u0 + 1];
            float y0 = delta[t0], y1 = delta[t1];
            vnode[u0] = y0; vnode[u0 + 1] = y1;
        } else {
            for (int u = u0; u < N; ++u) vnode[u] = delta[tpre[u]];
        }
    }
    grid_barrier(bar_cnt, bar_gen, gridDim.x);

    // ---- Phase 4: out[i] = vnode[nop[i]], nt-hints keep vnode L2-resident ----
    {
        const int stride8 = gridDim.x * SCAN_THREADS * 8;
        for (int i = (blockIdx.x * SCAN_THREADS + tid) * 8; i < P; i += stride8) {
            if (i + 8 <= P) {
                v4i n0 = __builtin_nontemporal_load((const v4i*)(nop + i));
                v4i n1 = __builtin_nontemporal_load((const v4i*)(nop + i + 4));
                v4f o0 = { vnode[n0.x], vnode[n0.y], vnode[n0.z], vnode[n0.w] };
                v4f o1 = { vnode[n1.x], vnode[n1.y], vnode[n1.z], vnode[n1.w] };
                __builtin_nontemporal_store(o0, (v4f*)(out + i));
                __builtin_nontemporal_store(o1, (v4f*)(out + i + 4));
            } else {
                for (int j = i; j < P; ++j) out[j] = vnode[nop[j]];
            }
        }
    }
}

// ---------------------------------------------------------------------------
// Tiny-workspace fallback path (separate kernels, unchanged).
__global__ void k2_partials(const float* __restrict__ delta,
                            float* __restrict__ partials, int T) {
    __shared__ float sdata[SCAN_THREADS / 64];
    int base = blockIdx.x * CHUNK + threadIdx.x * EPT;
    float s = 0.0f;
    if (base + EPT <= T) {
        v4f v0 = *(const v4f*)(delta + base);
        v4f v1 = *(const v4f*)(delta + base + 4);
        s = v0.x + v0.y + v0.z + v0.w + v1.x + v1.y + v1.z + v1.w;
    } else {
        for (int i = 0; i < EPT; ++i)
            if (base + i < T) s += delta[base + i];
    }
    #pragma unroll
    for (int d = 32; d > 0; d >>= 1) s += __shfl_down(s, d, 64);
    int lane = threadIdx.x & 63, wid = threadIdx.x >> 6;
    if (lane == 0) sdata[wid] = s;
    __syncthreads();
    if (threadIdx.x == 0)
        partials[blockIdx.x] = sdata[0] + sdata[1] + sdata[2] + sdata[3];
}

__global__ void k4_scan_chunks(float* __restrict__ data,
                               const float* __restrict__ partials, int T) {
    __shared__ float wavesums[SCAN_THREADS / 64];
    __shared__ float redsum[SCAN_THREADS / 64];
    int lane = threadIdx.x & 63, wid = threadIdx.x >> 6;
    float c = 0.0f;
    for (int i = threadIdx.x; i < blockIdx.x; i += SCAN_THREADS)
        c += partials[i];
    #pragma unroll
    for (int d = 32; d > 0; d >>= 1) c += __shfl_down(c, d, 64);
    if (lane == 0) redsum[wid] = c;

    int base = blockIdx.x * CHUNK + threadIdx.x * EPT;
    float v[EPT];
    bool full = (base + EPT <= T);
    if (full) {
        v4f v0 = *(const v4f*)(data + base);
        v4f v1 = *(const v4f*)(data + base + 4);
        v[0]=v0.x; v[1]=v0.y; v[2]=v0.z; v[3]=v0.w;
        v[4]=v1.x; v[5]=v1.y; v[6]=v1.z; v[7]=v1.w;
    } else {
        for (int i = 0; i < EPT; ++i)
            v[i] = (base + i < T) ? data[base + i] : 0.0f;
    }
    float run = 0.0f;
    #pragma unroll
    for (int i = 0; i < EPT; ++i) { run += v[i]; v[i] = run; }
    float tot = run;
    float x = tot;
    #pragma unroll
    for (int d = 1; d < 64; d <<= 1) {
        float y = __shfl_up(x, d, 64);
        if (lane >= d) x += y;
    }
    if (lane == 63) wavesums[wid] = x;
    __syncthreads();
    float woff = 0.0f, offset = redsum[0] + redsum[1] + redsum[2] + redsum[3];
    #pragma unroll
    for (int i = 0; i < SCAN_THREADS / 64; ++i)
        if (i < wid) woff += wavesums[i];
    float add = (x - tot) + woff + offset;
    if (full) {
        v4f o0 = { v[0]+add, v[1]+add, v[2]+add, v[3]+add };
        v4f o1 = { v[4]+add, v[5]+add, v[6]+add, v[7]+add };
        *(v4f*)(data + base)     = o0;
        *(v4f*)(data + base + 4) = o1;
    } else {
        for (int i = 0; i < EPT; ++i)
            if (base + i < T) data[base + i] = v[i] + add;
    }
}

__global__ void k6_direct(const float* __restrict__ ycum,
                          const int* __restrict__ tpre,
                          const int* __restrict__ nop,
                          float* __restrict__ out, int P) {
    int i = (blockIdx.x * blockDim.x + threadIdx.x) * 4;
    if (i + 4 <= P) {
        v4i n = *(const v4i*)(nop + i);
        v4f o = { ycum[tpre[n.x]], ycum[tpre[n.y]], ycum[tpre[n.z]], ycum[tpre[n.w]] };
        *(v4f*)(out + i) = o;
    } else {
        for (; i < P; ++i) out[i] = ycum[tpre[nop[i]]];
    }
}

extern "C" void kernel_launch(void* const* d_in, const int* in_sizes, int n_in,
                              void* d_out, int out_size, void* d_ws, size_t ws_size,
                              hipStream_t stream) {
    const float* weight   = (const float*)d_in[0];
    const float* bias     = (const float*)d_in[1];
    const float* residues = (const float*)d_in[2];
    const float* attrs    = (const float*)d_in[3];
    const int*   tpre     = (const int*)d_in[4];
    const int*   tpost    = (const int*)d_in[5];
    const int*   nop      = (const int*)d_in[6];
    float* out = (float*)d_out;

    const int N = in_sizes[2];        // 500,000
    const int T = 2 * N;              // 1,000,000
    const int P = out_size;           // 8,388,608
    const int numChunks = (T + CHUNK - 1) / CHUNK;   // 489

    size_t needFull = (size_t)(T + N + 1024) * sizeof(float);
    size_t needMid  = (size_t)(N + 1024) * sizeof(float);

    float* delta;
    float* vnode    = nullptr;
    float* partials;
    int*   bar      = nullptr;        // [0]=cnt, [1]=gen
    int tier;

    if (ws_size >= needFull) {
        delta    = (float*)d_ws;
        vnode    = delta + T;
        partials = vnode + N;
        bar      = (int*)(partials + 512);   // numChunks(489) <= 512, slack to 1024
        tier = 2;
    } else if (ws_size >= needMid) {
        delta    = out;               // dead until phase 4 rewrites it fully
        vnode    = (float*)d_ws;
        partials = vnode + N;
        bar      = (int*)(partials + 512);
        tier = 1;
    } else {
        delta    = out;
        partials = (float*)d_ws;
        tier = 0;
    }

    k1_filter_scatter<<<(N / 2 + 255) / 256, 256, 0, stream>>>(
        attrs, weight, bias, residues, tpre, tpost, delta, bar, N);

    if (tier >= 1) {
        float* deltaArg = delta;
        float* partialsArg = partials;
        float* vnodeArg = vnode;
        const int* tpreArg = tpre;
        const int* nopArg = nop;
        float* outArg = out;
        int* cntArg = bar;
        int* genArg = bar + 1;
        int nN = N, nT = T, nP = P, nC = numChunks;
        void* args[] = { &deltaArg, &partialsArg, &vnodeArg, &tpreArg, &nopArg,
                         &outArg, &cntArg, &genArg, &nN, &nT, &nP, &nC };
        (void)hipLaunchCooperativeKernel(k_fused, dim3(COOP_BLOCKS),
                                         dim3(SCAN_THREADS), args, 0, stream);
    } else {
        k2_partials<<<numChunks, SCAN_THREADS, 0, stream>>>(delta, partials, T);
        k4_scan_chunks<<<numChunks, SCAN_THREADS, 0, stream>>>(delta, partials, T);
        int gatherBlocks = (P / 4 + 255) / 256;
        k6_direct<<<gatherBlocks, 256, 0, stream>>>(delta, tpre, nop, out, P);
    }
}

// Round 4
// 188.270 us; speedup vs baseline: 2.6207x; 2.6207x over previous
//
#include <hip/hip_runtime.h>

#define SCAN_THREADS 256
#define EPT 8
#define CHUNK (SCAN_THREADS * EPT)   // 2048 elements per scan chunk
#define CHUNK_SHIFT 11               // log2(CHUNK)
#define MAX_CHUNKS 1024              // LDS histogram bins (T up to 2M)

typedef int   v2i __attribute__((ext_vector_type(2)));
typedef int   v4i __attribute__((ext_vector_type(4)));
typedef float v2f __attribute__((ext_vector_type(2)));
typedef float v4f __attribute__((ext_vector_type(4)));

// ---------------------------------------------------------------------------
// K1: filtered = residues * sigmoid(attrs @ w + b); scatter +/- into delta,
// AND accumulate per-chunk partial sums via LDS histogram + global atomics
// (replaces the old k2 kernel + its ~4MB delta re-read + one kernel boundary).
// partials must be zeroed before this kernel (hipMemsetAsync in launch).
// Streamed inputs are nt-loaded so delta's scattered stores stay L2-resident
// for k4's re-read.
__global__ void k1_filter_scatter_hist(const float* __restrict__ attrs,
                                       const float* __restrict__ weight,
                                       const float* __restrict__ bias,
                                       const float* __restrict__ residues,
                                       const int* __restrict__ tpre,
                                       const int* __restrict__ tpost,
                                       float* __restrict__ delta,
                                       float* __restrict__ partials,
                                       int N, int numChunks) {
    __shared__ float hist[MAX_CHUNKS];
    for (int i = threadIdx.x; i < numChunks; i += SCAN_THREADS) hist[i] = 0.0f;
    __syncthreads();

    int u0 = (blockIdx.x * blockDim.x + threadIdx.x) * 2;
    v4f w0 = *(const v4f*)weight;
    v4f w1 = *(const v4f*)(weight + 4);
    float b = bias[0];
    if (u0 + 2 <= N) {
        v2f rr = __builtin_nontemporal_load((const v2f*)(residues + u0));
        v2i pr = __builtin_nontemporal_load((const v2i*)(tpre + u0));
        v2i po = __builtin_nontemporal_load((const v2i*)(tpost + u0));
        v4f a00 = __builtin_nontemporal_load((const v4f*)(attrs + (size_t)u0 * 8));
        v4f a01 = __builtin_nontemporal_load((const v4f*)(attrs + (size_t)u0 * 8 + 4));
        v4f a10 = __builtin_nontemporal_load((const v4f*)(attrs + (size_t)u0 * 8 + 8));
        v4f a11 = __builtin_nontemporal_load((const v4f*)(attrs + (size_t)u0 * 8 + 12));
        float l0 = a00.x*w0.x + a00.y*w0.y + a00.z*w0.z + a00.w*w0.w +
                   a01.x*w1.x + a01.y*w1.y + a01.z*w1.z + a01.w*w1.w + b;
        float l1 = a10.x*w0.x + a10.y*w0.y + a10.z*w0.z + a10.w*w0.w +
                   a11.x*w1.x + a11.y*w1.y + a11.z*w1.z + a11.w*w1.w + b;
        float f0 = rr.x / (1.0f + __expf(-l0));
        float f1 = rr.y / (1.0f + __expf(-l1));
        delta[pr.x] =  f0; delta[pr.y] =  f1;
        delta[po.x] = -f0; delta[po.y] = -f1;
        atomicAdd(&hist[pr.x >> CHUNK_SHIFT],  f0);
        atomicAdd(&hist[pr.y >> CHUNK_SHIFT],  f1);
        atomicAdd(&hist[po.x >> CHUNK_SHIFT], -f0);
        atomicAdd(&hist[po.y >> CHUNK_SHIFT], -f1);
    } else {
        for (int u = u0; u < N; ++u) {
            float logit = b;
            #pragma unroll
            for (int k = 0; k < 8; ++k) logit += attrs[(size_t)u * 8 + k] * weight[k];
            float f = residues[u] / (1.0f + __expf(-logit));
            int pre = tpre[u], pos = tpost[u];
            delta[pre] =  f;
            delta[pos] = -f;
            atomicAdd(&hist[pre >> CHUNK_SHIFT],  f);
            atomicAdd(&hist[pos >> CHUNK_SHIFT], -f);
        }
    }
    __syncthreads();
    for (int i = threadIdx.x; i < numChunks; i += SCAN_THREADS)
        atomicAdd(&partials[i], hist[i]);
}

// Plain k1 (no hist) for the numChunks > MAX_CHUNKS fallback.
__global__ void k1_filter_scatter(const float* __restrict__ attrs,
                                  const float* __restrict__ weight,
                                  const float* __restrict__ bias,
                                  const float* __restrict__ residues,
                                  const int* __restrict__ tpre,
                                  const int* __restrict__ tpost,
                                  float* __restrict__ delta,
                                  int N) {
    int u0 = (blockIdx.x * blockDim.x + threadIdx.x) * 2;
    v4f w0 = *(const v4f*)weight;
    v4f w1 = *(const v4f*)(weight + 4);
    float b = bias[0];
    if (u0 + 2 <= N) {
        v2f rr = *(const v2f*)(residues + u0);
        v2i pr = *(const v2i*)(tpre + u0);
        v2i po = *(const v2i*)(tpost + u0);
        v4f a00 = *(const v4f*)(attrs + (size_t)u0 * 8);
        v4f a01 = *(const v4f*)(attrs + (size_t)u0 * 8 + 4);
        v4f a10 = *(const v4f*)(attrs + (size_t)u0 * 8 + 8);
        v4f a11 = *(const v4f*)(attrs + (size_t)u0 * 8 + 12);
        float l0 = a00.x*w0.x + a00.y*w0.y + a00.z*w0.z + a00.w*w0.w +
                   a01.x*w1.x + a01.y*w1.y + a01.z*w1.z + a01.w*w1.w + b;
        float l1 = a10.x*w0.x + a10.y*w0.y + a10.z*w0.z + a10.w*w0.w +
                   a11.x*w1.x + a11.y*w1.y + a11.z*w1.z + a11.w*w1.w + b;
        float f0 = rr.x / (1.0f + __expf(-l0));
        float f1 = rr.y / (1.0f + __expf(-l1));
        delta[pr.x] =  f0; delta[pr.y] =  f1;
        delta[po.x] = -f0; delta[po.y] = -f1;
    } else {
        for (int u = u0; u < N; ++u) {
            float logit = b;
            #pragma unroll
            for (int k = 0; k < 8; ++k) logit += attrs[(size_t)u * 8 + k] * weight[k];
            float f = residues[u] / (1.0f + __expf(-logit));
            delta[tpre[u]]  =  f;
            delta[tpost[u]] = -f;
        }
    }
}

// ---------------------------------------------------------------------------
// K2 (fallback only): per-chunk partial sums.
__global__ void k2_partials(const float* __restrict__ delta,
                            float* __restrict__ partials, int T) {
    __shared__ float sdata[SCAN_THREADS / 64];
    int base = blockIdx.x * CHUNK + threadIdx.x * EPT;
    float s = 0.0f;
    if (base + EPT <= T) {
        v4f v0 = *(const v4f*)(delta + base);
        v4f v1 = *(const v4f*)(delta + base + 4);
        s = v0.x + v0.y + v0.z + v0.w + v1.x + v1.y + v1.z + v1.w;
    } else {
        for (int i = 0; i < EPT; ++i)
            if (base + i < T) s += delta[base + i];
    }
    #pragma unroll
    for (int d = 32; d > 0; d >>= 1) s += __shfl_down(s, d, 64);
    int lane = threadIdx.x & 63, wid = threadIdx.x >> 6;
    if (lane == 0) sdata[wid] = s;
    __syncthreads();
    if (threadIdx.x == 0)
        partials[blockIdx.x] = sdata[0] + sdata[1] + sdata[2] + sdata[3];
}

// ---------------------------------------------------------------------------
// K4: in-place inclusive scan of each chunk; each block derives its own
// offset by reducing partials[0..blockIdx.x) (L2-hot floats).
__global__ void k4_scan_chunks(float* __restrict__ data,
                               const float* __restrict__ partials, int T) {
    __shared__ float wavesums[SCAN_THREADS / 64];
    __shared__ float redsum[SCAN_THREADS / 64];
    int lane = threadIdx.x & 63, wid = threadIdx.x >> 6;

    float c = 0.0f;
    for (int i = threadIdx.x; i < blockIdx.x; i += SCAN_THREADS)
        c += partials[i];
    #pragma unroll
    for (int d = 32; d > 0; d >>= 1) c += __shfl_down(c, d, 64);
    if (lane == 0) redsum[wid] = c;

    int base = blockIdx.x * CHUNK + threadIdx.x * EPT;
    float v[EPT];
    bool full = (base + EPT <= T);
    if (full) {
        v4f v0 = *(const v4f*)(data + base);
        v4f v1 = *(const v4f*)(data + base + 4);
        v[0]=v0.x; v[1]=v0.y; v[2]=v0.z; v[3]=v0.w;
        v[4]=v1.x; v[5]=v1.y; v[6]=v1.z; v[7]=v1.w;
    } else {
        for (int i = 0; i < EPT; ++i)
            v[i] = (base + i < T) ? data[base + i] : 0.0f;
    }
    float run = 0.0f;
    #pragma unroll
    for (int i = 0; i < EPT; ++i) { run += v[i]; v[i] = run; }
    float tot = run;
    float x = tot;
    #pragma unroll
    for (int d = 1; d < 64; d <<= 1) {
        float y = __shfl_up(x, d, 64);
        if (lane >= d) x += y;
    }
    if (lane == 63) wavesums[wid] = x;
    __syncthreads();
    float woff = 0.0f, offset = redsum[0] + redsum[1] + redsum[2] + redsum[3];
    #pragma unroll
    for (int i = 0; i < SCAN_THREADS / 64; ++i)
        if (i < wid) woff += wavesums[i];
    float add = (x - tot) + woff + offset;
    if (full) {
        v4f o0 = { v[0]+add, v[1]+add, v[2]+add, v[3]+add };
        v4f o1 = { v[4]+add, v[5]+add, v[6]+add, v[7]+add };
        *(v4f*)(data + base)     = o0;
        *(v4f*)(data + base + 4) = o1;
    } else {
        for (int i = 0; i < EPT; ++i)
            if (base + i < T) data[base + i] = v[i] + add;
    }
}

// ---------------------------------------------------------------------------
// K5: vnode[u] = ycum[tpre[u]]; 4 nodes/thread, nt index loads.
// vnode store stays PLAIN so it lands in L2 for k6's gathers.
__global__ void k5_node_values(const float* __restrict__ ycum,
                               const int* __restrict__ tpre,
                               float* __restrict__ vnode, int N) {
    int u0 = (blockIdx.x * blockDim.x + threadIdx.x) * 4;
    if (u0 + 4 <= N) {
        v4i t = __builtin_nontemporal_load((const v4i*)(tpre + u0));
        v4f y = { ycum[t.x], ycum[t.y], ycum[t.z], ycum[t.w] };
        *(v4f*)(vnode + u0) = y;
    } else {
        for (int u = u0; u < N; ++u) vnode[u] = ycum[tpre[u]];
    }
}

// ---------------------------------------------------------------------------
// K6: per-pixel gather, 8 px/thread. nt on the 67MB nop/out streams so the
// 2MB vnode gather table stays L2-resident; vnode gathers stay plain-cached.
__global__ void k6_gather(const float* __restrict__ vnode,
                          const int* __restrict__ nop,
                          float* __restrict__ out, int P) {
    int i = (blockIdx.x * blockDim.x + threadIdx.x) * 8;
    if (i + 8 <= P) {
        v4i n0 = __builtin_nontemporal_load((const v4i*)(nop + i));
        v4i n1 = __builtin_nontemporal_load((const v4i*)(nop + i + 4));
        v4f o0 = { vnode[n0.x], vnode[n0.y], vnode[n0.z], vnode[n0.w] };
        v4f o1 = { vnode[n1.x], vnode[n1.y], vnode[n1.z], vnode[n1.w] };
        __builtin_nontemporal_store(o0, (v4f*)(out + i));
        __builtin_nontemporal_store(o1, (v4f*)(out + i + 4));
    } else {
        for (; i < P; ++i) out[i] = vnode[nop[i]];
    }
}

// K6 fallback: direct double gather (tiny-ws tier only).
__global__ void k6_direct(const float* __restrict__ ycum,
                          const int* __restrict__ tpre,
                          const int* __restrict__ nop,
                          float* __restrict__ out, int P) {
    int i = (blockIdx.x * blockDim.x + threadIdx.x) * 4;
    if (i + 4 <= P) {
        v4i n = *(const v4i*)(nop + i);
        v4f o = { ycum[tpre[n.x]], ycum[tpre[n.y]], ycum[tpre[n.z]], ycum[tpre[n.w]] };
        *(v4f*)(out + i) = o;
    } else {
        for (; i < P; ++i) out[i] = ycum[tpre[nop[i]]];
    }
}

extern "C" void kernel_launch(void* const* d_in, const int* in_sizes, int n_in,
                              void* d_out, int out_size, void* d_ws, size_t ws_size,
                              hipStream_t stream) {
    const float* weight   = (const float*)d_in[0];
    const float* bias     = (const float*)d_in[1];
    const float* residues = (const float*)d_in[2];
    const float* attrs    = (const float*)d_in[3];
    const int*   tpre     = (const int*)d_in[4];
    const int*   tpost    = (const int*)d_in[5];
    const int*   nop      = (const int*)d_in[6];
    float* out = (float*)d_out;

    const int N = in_sizes[2];        // 500,000
    const int T = 2 * N;              // 1,000,000
    const int P = out_size;           // 8,388,608
    const int numChunks = (T + CHUNK - 1) / CHUNK;   // 489

    size_t needFull = (size_t)(T + N + 1024) * sizeof(float);
    size_t needMid  = (size_t)(N + 1024) * sizeof(float);

    float* delta;
    float* vnode    = nullptr;
    float* partials;
    bool useVnode = true;

    if (ws_size >= needFull) {
        delta    = (float*)d_ws;
        vnode    = delta + T;
        partials = vnode + N;
    } else if (ws_size >= needMid) {
        delta    = out;               // dead until k6 rewrites it fully
        vnode    = (float*)d_ws;
        partials = vnode + N;
    } else {
        delta    = out;
        partials = (float*)d_ws;
        useVnode = false;
    }

    const int k1Blocks = (N / 2 + 255) / 256;

    if (numChunks <= MAX_CHUNKS) {
        // partials accumulated atomically in k1 -> must be zeroed first.
        (void)hipMemsetAsync(partials, 0, (size_t)numChunks * sizeof(float), stream);
        k1_filter_scatter_hist<<<k1Blocks, 256, 0, stream>>>(
            attrs, weight, bias, residues, tpre, tpost, delta, partials, N, numChunks);
    } else {
        k1_filter_scatter<<<k1Blocks, 256, 0, stream>>>(
            attrs, weight, bias, residues, tpre, tpost, delta, N);
        k2_partials<<<numChunks, SCAN_THREADS, 0, stream>>>(delta, partials, T);
    }

    k4_scan_chunks<<<numChunks, SCAN_THREADS, 0, stream>>>(delta, partials, T);

    if (useVnode) {
        k5_node_values<<<(N / 4 + 255) / 256, 256, 0, stream>>>(delta, tpre, vnode, N);
        int gatherBlocks = (P / 8 + 255) / 256;
        k6_gather<<<gatherBlocks, 256, 0, stream>>>(vnode, nop, out, P);
    } else {
        int gatherBlocks = (P / 4 + 255) / 256;
        k6_direct<<<gatherBlocks, 256, 0, stream>>>(delta, tpre, nop, out, P);
    }
}